// Round 7
// baseline (196.839 us; speedup 1.0000x reference)
//
#include <hip/hip_runtime.h>

// SetEq4to4: out[n,so,i,j,k,l] = sum over 69 basis ops (A,B) + bias.
// n=2, d=8, so=8, N=32, basis=69.
//
// Pipeline (memset + 3 regular launches):
//   MS hipMemsetAsync: zero red2_23 + red1 accumulation regions (73,728 B).
//   KR k_red3 (1024 blk x 512 thr): x -> r012,r013,r023 (plane blocks) and r123
//              (col blocks). Epilogues emit ALL red2 (01)(02)(03) direct,
//              (12)(13) direct, (23) via f32 atomicAdd; ALL red1 (0)(1) direct,
//              (2)(3) via atomicAdd.  [verified R5/R6]
//   KF k_mixF (2048 blk x 256 thr, so split 8-way): latency-pipelined U3 mix.
//              All long-latency loads (v[4][8] main mix + rv[6][8] fold batch +
//              subset-fold batches) issue BEFORE the first sync; per-thread
//              C-fold results stay in registers (consumed at same (p2,p3)).
//   K6 k_final (XCD-chunked swizzle): out = sum_d c68*x + U012+U013+U023+U123

constexpr size_t R3SZ  = 524288;   // per-a: 16 nd * 32768
constexpr size_t R2SZ  = 16384;    // per-b2: 16 nd * 1024
constexpr size_t R1SZ  = 512;      // per-b1: 16 nd * 32
constexpr size_t R3OFF = 0;
constexpr size_t R2OFF = R3OFF + 4 * R3SZ;   // red2: b2 0..5 = (01)(02)(03)(12)(13)(23)
constexpr size_t R1OFF = R2OFF + 6 * R2SZ;   // red1: b1 0..3 = (0)(1)(2)(3)
constexpr size_t U3OFF = R1OFF + 4 * R1SZ;
// total ws floats: U3OFF + 4*R3SZ = 4297728  (~17.2 MiB)
// zeroed-by-memset region: [R2OFF+5*R2SZ, R1OFF+4*R1SZ) = 18432 floats = 73728 B

// ---------------- KR: rank-3 reductions + ALL red2/red1 ----------------
__global__ __launch_bounds__(512) void k_red3(const float* __restrict__ x,
                                              float* __restrict__ ws) {
    __shared__ float4 cp[32][4][8];   // [j][k-octet][l4] col partials (16 KiB)
    __shared__ float  b012[1024];     // [j][k] row sums (4 KiB)
    __shared__ float4 a2[256];        // park buffer (4 KiB)
    const int bid  = blockIdx.x;
    const int t    = threadIdx.x;
    const int half = t >> 8;          // parity of the loop axis handled by this half
    const int tt   = t & 255;
    const int k    = tt >> 3;         // k index owned by this thread
    const int l4   = tt & 7;          // l-quad owned by this thread

    if (bid < 512) {
        // -------- plane blocks: fixed (nd, i), loop over j --------
        const int i    = bid & 31;
        const int nd   = bid >> 5;
        const int w4   = (t >> 6) & 3;   // which k-octet this wave covers
        const int lane = t & 63;
        const float* xp = x + ((size_t)nd << 20) + ((size_t)i << 15) + k * 32 + l4 * 4;
        float4 acc = {0.f, 0.f, 0.f, 0.f};           // r023[i,k,l] accumulator
        #pragma unroll
        for (int it = 0; it < 16; ++it) {
            const int j = it * 2 + half;
            float4 v = *(const float4*)(xp + j * 1024);
            acc.x += v.x; acc.y += v.y; acc.z += v.z; acc.w += v.w;
            // r012[i,j,k] = sum over l: hsum + butterfly over lane bits 0..2
            float h = v.x + v.y + v.z + v.w;
            h += __shfl_xor(h, 1); h += __shfl_xor(h, 2); h += __shfl_xor(h, 4);
            if (l4 == 0) b012[j * 32 + k] = h;
            // col partials over this wave's 8 k's: butterfly over lane bits 3..5
            v.x += __shfl_xor(v.x, 8);  v.y += __shfl_xor(v.y, 8);
            v.z += __shfl_xor(v.z, 8);  v.w += __shfl_xor(v.w, 8);
            v.x += __shfl_xor(v.x, 16); v.y += __shfl_xor(v.y, 16);
            v.z += __shfl_xor(v.z, 16); v.w += __shfl_xor(v.w, 16);
            v.x += __shfl_xor(v.x, 32); v.y += __shfl_xor(v.y, 32);
            v.z += __shfl_xor(v.z, 32); v.w += __shfl_xor(v.w, 32);
            if (lane < 8) cp[j][w4][lane] = v;
        }
        if (half == 1) a2[tt] = acc;                 // park for r023 combine
        __syncthreads();
        const size_t base = ((size_t)nd << 15) + ((size_t)i << 10);
        // r012 write: [i][j*32+k], 2 floats/thread, fully coalesced
        *(float2*)(ws + R3OFF + base + 2 * t) = *(const float2*)(b012 + 2 * t);
        if (half == 0) {
            // r013[i,j,l]: combine the 4 k-octet partials
            const int j = tt >> 3, lj = tt & 7;
            float4 s0 = cp[j][0][lj], s1 = cp[j][1][lj];
            float4 s2 = cp[j][2][lj], s3 = cp[j][3][lj];
            float4 s;
            s.x = s0.x + s1.x + s2.x + s3.x;
            s.y = s0.y + s1.y + s2.y + s3.y;
            s.z = s0.z + s1.z + s2.z + s3.z;
            s.w = s0.w + s1.w + s2.w + s3.w;
            *(float4*)(ws + R3OFF + R3SZ + base + j * 32 + lj * 4) = s;
            // r023[i,k,l]: merge the two j-parity halves
            float4 b = a2[tt];
            a2[tt] = s;                              // repurpose: a2 (as float[1024]) = r013[j][l]
            acc.x += b.x; acc.y += b.y; acc.z += b.z; acc.w += b.w;
            *(float4*)(ws + R3OFF + 2 * R3SZ + base + k * 32 + l4 * 4) = acc;
            // red2_23[k,l] += r023[i,k,l]  (cross-block i-sum via f32 atomics;
            // region zeroed by the stream-head memset)
            float* r23 = ws + R2OFF + 5 * R2SZ + (size_t)nd * 1024 + k * 32 + l4 * 4;
            atomicAdd(r23 + 0, acc.x); atomicAdd(r23 + 1, acc.y);
            atomicAdd(r23 + 2, acc.z); atomicAdd(r23 + 3, acc.w);
        }
        __syncthreads();
        // epilogue 2: red2 (01)(02)(03) + red1 (0)(2)(3) for this i
        const size_t r2b = (size_t)nd * 1024 + (size_t)i * 32;
        if (t < 32) {
            // red2_01[i][j=t] = sum_k b012[t*32+k]  (skewed k to avoid bank conflicts)
            float s = 0.f;
            #pragma unroll
            for (int kk = 0; kk < 32; ++kk) s += b012[t * 32 + ((kk + t) & 31)];
            ws[R2OFF + 0 * R2SZ + r2b + t] = s;
            // red1_0[i] = sum_j red2_01[i][j]: butterfly over lanes 0..31 (wave 0)
            float r = s;
            r += __shfl_xor(r, 1);  r += __shfl_xor(r, 2);  r += __shfl_xor(r, 4);
            r += __shfl_xor(r, 8);  r += __shfl_xor(r, 16);
            if (t == 0) ws[R1OFF + 0 * R1SZ + (size_t)nd * 32 + i] = r;
        } else if (t < 64) {
            // red2_02[i][k] = sum_j b012[j*32+k]  (bank = k, conflict-free)
            const int kc = t - 32;
            float s = 0.f;
            #pragma unroll
            for (int j = 0; j < 32; ++j) s += b012[j * 32 + kc];
            ws[R2OFF + 1 * R2SZ + r2b + kc] = s;
            // red1_2[k] += red2_02[i][k]  (cross-block i-sum)
            atomicAdd(ws + R1OFF + 2 * R1SZ + (size_t)nd * 32 + kc, s);
        } else if (t < 96) {
            // red2_03[i][l] = sum_j r013[i][j][l]  (a2 flat view = [j][l], bank = l)
            const int l = t - 64;
            const float* af = (const float*)a2;
            float s = 0.f;
            #pragma unroll
            for (int j = 0; j < 32; ++j) s += af[j * 32 + l];
            ws[R2OFF + 2 * R2SZ + r2b + l] = s;
            // red1_3[l] += red2_03[i][l]  (cross-block i-sum)
            atomicAdd(ws + R1OFF + 3 * R1SZ + (size_t)nd * 32 + l, s);
        }
    } else {
        // -------- col blocks: fixed (nd, j), loop over i --------
        const int bb = bid - 512;
        const int j  = bb & 31;
        const int nd = bb >> 5;
        const float* xp = x + ((size_t)nd << 20) + (size_t)j * 1024 + (size_t)tt * 4;
        float4 acc = {0.f, 0.f, 0.f, 0.f};
        #pragma unroll
        for (int it = 0; it < 16; ++it) {
            const int i = it * 2 + half;
            float4 v = *(const float4*)(xp + ((size_t)i << 15));
            acc.x += v.x; acc.y += v.y; acc.z += v.z; acc.w += v.w;
        }
        if (half == 1) a2[tt] = acc;
        __syncthreads();
        const size_t r2b = (size_t)nd * 1024 + (size_t)j * 32;
        if (half == 0) {
            float4 b = a2[tt];
            acc.x += b.x; acc.y += b.y; acc.z += b.z; acc.w += b.w;
            *(float4*)(ws + R3OFF + 3 * R3SZ + ((size_t)nd << 15)
                       + ((size_t)j << 10) + tt * 4) = acc;   // r123[j][k][l]
            // red2_12[j][k] = sum_l r123: hsum + butterfly over lane bits 0..2
            float h = acc.x + acc.y + acc.z + acc.w;
            h += __shfl_xor(h, 1); h += __shfl_xor(h, 2); h += __shfl_xor(h, 4);
            if ((t & 7) == 0) {
                ws[R2OFF + 3 * R2SZ + r2b + k] = h;
                b012[k] = h;                          // park for red1_1 reduce
            }
            // red2_13[j][l] = sum_k r123: butterfly lane bits 3..5, then cross-wave
            float4 c2 = acc;
            c2.x += __shfl_xor(c2.x, 8);  c2.y += __shfl_xor(c2.y, 8);
            c2.z += __shfl_xor(c2.z, 8);  c2.w += __shfl_xor(c2.w, 8);
            c2.x += __shfl_xor(c2.x, 16); c2.y += __shfl_xor(c2.y, 16);
            c2.z += __shfl_xor(c2.z, 16); c2.w += __shfl_xor(c2.w, 16);
            c2.x += __shfl_xor(c2.x, 32); c2.y += __shfl_xor(c2.y, 32);
            c2.z += __shfl_xor(c2.z, 32); c2.w += __shfl_xor(c2.w, 32);
            if ((t & 63) < 8) cp[0][t >> 6][t & 63] = c2;
        }
        __syncthreads();
        if (t < 8) {
            float4 s0 = cp[0][0][t], s1 = cp[0][1][t];
            float4 s2 = cp[0][2][t], s3 = cp[0][3][t];
            float4 s;
            s.x = s0.x + s1.x + s2.x + s3.x;
            s.y = s0.y + s1.y + s2.y + s3.y;
            s.z = s0.z + s1.z + s2.z + s3.z;
            s.w = s0.w + s1.w + s2.w + s3.w;
            *(float4*)(ws + R2OFF + 4 * R2SZ + r2b + t * 4) = s;
        }
        if (t < 32) {
            // red1_1[j] = sum_k red2_12[j][k]: butterfly over lanes 0..31 (wave 0)
            float r = b012[t];
            r += __shfl_xor(r, 1);  r += __shfl_xor(r, 2);  r += __shfl_xor(r, 4);
            r += __shfl_xor(r, 8);  r += __shfl_xor(r, 16);
            if (t == 0) ws[R1OFF + 1 * R1SZ + (size_t)nd * 32 + j] = r;
        }
    }
}

// ---------------- KF: latency-pipelined U3 mix, so split 8-way ----------------
// block = n(1) | so(3) | cb(7); c = cb*256+tt; p1 = cb>>2 (fixed),
// p2 = (cb&3)*8 + (tt>>5), p3 = tt&31.
__global__ __launch_bounds__(256) void k_mixF(const float* __restrict__ coefs,
                                              const float* __restrict__ bias,
                                              float* __restrict__ ws) {
    __shared__ float cs[8][69];        // this so's coef slice  (2.2 KB)
    __shared__ float tA[8];            // T2f[b2=0] @ (p1, p2b+p2')
    __shared__ float tB[2][32];        // T2f[1],[2] @ (p1, p3)
    __shared__ float t1[4][32];        // T1f[b1] @ p
    const int tt  = threadIdx.x;
    const int blk = blockIdx.x;        // 2048 = n(1) | so(3) | cb(7)
    const int cb  = blk & 127;
    const int so  = (blk >> 7) & 7;
    const int n   = blk >> 10;
    const int p1  = cb >> 2;
    const int p2b = (cb & 3) * 8;
    const int p2p = tt >> 5, p3 = tt & 31;
    const int c   = cb * 256 + tt;

    // ---- stage coef slice (552 floats) ----
    for (int idx = tt; idx < 552; idx += 256) {
        const int d = idx / 69, r = idx - d * 69;
        cs[d][r] = coefs[(d * 8 + so) * 69 + r];
    }
    const float bso = bias[so];

    // ---- issue ALL long-latency loads before the first sync ----
    float v[4][8];                               // main-phase red3 fragments
    #pragma unroll
    for (int a = 0; a < 4; ++a)
        #pragma unroll
        for (int d = 0; d < 8; ++d)
            v[a][d] = ws[R3OFF + (size_t)a * R3SZ + (size_t)(n * 8 + d) * 32768 + c];
    float rv[6][8];                              // C-fold batch @ (p2,p3)
    {
        const int pq = (p2b + p2p) * 32 + p3;
        #pragma unroll
        for (int a2 = 0; a2 < 6; ++a2)
            #pragma unroll
            for (int d = 0; d < 8; ++d)
                rv[a2][d] = ws[R2OFF + (size_t)a2 * R2SZ
                               + (size_t)(n * 8 + d) * 1024 + pq];
    }
    float rvS[6][8];                             // subset-fold batches (disjoint roles)
    if (tt < 32) {                               // B: @ (p1, p3=tt)
        const int pq = p1 * 32 + tt;
        #pragma unroll
        for (int a2 = 0; a2 < 6; ++a2)
            #pragma unroll
            for (int d = 0; d < 8; ++d)
                rvS[a2][d] = ws[R2OFF + (size_t)a2 * R2SZ
                                + (size_t)(n * 8 + d) * 1024 + pq];
    } else if (tt < 40) {                        // A: @ (p1, p2b+(tt-32))
        const int pq = p1 * 32 + p2b + (tt - 32);
        #pragma unroll
        for (int a2 = 0; a2 < 6; ++a2)
            #pragma unroll
            for (int d = 0; d < 8; ++d)
                rvS[a2][d] = ws[R2OFF + (size_t)a2 * R2SZ
                                + (size_t)(n * 8 + d) * 1024 + pq];
    } else if (tt >= 64 && tt < 96) {            // T1: red1[a1][d][p=tt-64]
        const int p = tt - 64;
        #pragma unroll
        for (int a1 = 0; a1 < 4; ++a1)
            #pragma unroll
            for (int d = 0; d < 8; ++d)
                rvS[a1][d] = ws[R1OFF + (size_t)a1 * R1SZ
                                + (size_t)(n * 8 + d) * 32 + p];
    }
    __syncthreads();                             // cs visible

    // ---- C-fold: b2=3,4,5 @ own (p2,p3); results stay in registers ----
    float a6[3] = {0.f, 0.f, 0.f};
    #pragma unroll
    for (int a2 = 0; a2 < 6; ++a2)
        #pragma unroll
        for (int d = 0; d < 8; ++d) {
            const float* cc = &cs[d][16 + a2 * 6];
            a6[0] += cc[3] * rv[a2][d];
            a6[1] += cc[4] * rv[a2][d];
            a6[2] += cc[5] * rv[a2][d];
        }
    // ---- subset folds -> LDS ----
    if (tt < 32) {
        float b0 = 0.f, b1v = 0.f;
        #pragma unroll
        for (int a2 = 0; a2 < 6; ++a2)
            #pragma unroll
            for (int d = 0; d < 8; ++d) {
                const float* cc = &cs[d][16 + a2 * 6];
                b0  += cc[1] * rvS[a2][d];
                b1v += cc[2] * rvS[a2][d];
            }
        tB[0][tt] = b0; tB[1][tt] = b1v;
    } else if (tt < 40) {
        float a0 = 0.f;
        #pragma unroll
        for (int a2 = 0; a2 < 6; ++a2)
            #pragma unroll
            for (int d = 0; d < 8; ++d)
                a0 += cs[d][16 + a2 * 6] * rvS[a2][d];
        tA[tt - 32] = a0;
    } else if (tt >= 64 && tt < 96) {
        const int p = tt - 64;
        float s0 = 0.f, s1 = 0.f, s2 = 0.f, s3 = 0.f;
        #pragma unroll
        for (int a1 = 0; a1 < 4; ++a1)
            #pragma unroll
            for (int d = 0; d < 8; ++d) {
                const float* cc = &cs[d][a1 * 4];
                s0 += cc[0] * rvS[a1][d];
                s1 += cc[1] * rvS[a1][d];
                s2 += cc[2] * rvS[a1][d];
                s3 += cc[3] * rvS[a1][d];
            }
        t1[0][p] = s0; t1[1][p] = s1; t1[2][p] = s2; t1[3][p] = s3;
    }
    __syncthreads();

    // ---- main: U3[b] = mixed red3 + folds + bias ----
    #pragma unroll
    for (int b = 0; b < 4; ++b) {
        float s = 0.f;
        #pragma unroll
        for (int a = 0; a < 4; ++a)
            #pragma unroll
            for (int d = 0; d < 8; ++d)
                s += cs[d][52 + a * 4 + b] * v[a][d];
        if (b == 0) {
            s += tA[p2p] + tB[0][p3] + a6[0];
            s += t1[0][p1] + t1[1][p2b + p2p] + t1[2][p3];
            s += bso;
        } else if (b == 1) {
            s += tB[1][p3] + a6[1] + t1[3][p3];
        } else if (b == 2) {
            s += a6[2];
        }
        ws[U3OFF + (size_t)b * R3SZ + (size_t)(n * 8 + so) * 32768 + c] = s;
    }
}

// ---------------- K6: final broadcast-add + s=4 channel mix ----------------
__global__ __launch_bounds__(256) void k_final(const float* __restrict__ x,
                                               const float* __restrict__ coefs,
                                               const float* __restrict__ ws,
                                               float* __restrict__ out) {
    __shared__ float c68[64];
    if (threadIdx.x < 64) c68[threadIdx.x] = coefs[threadIdx.x * 69 + 68];
    __syncthreads();
    // XCD-chunked bijective swizzle (2048 % 8 == 0): blocks sharing i (and
    // thus the U023 slab + x panels) land on the same XCD's L2.
    const int rb = blockIdx.x;
    const int b  = ((rb & 7) << 8) | (rb >> 3);
    const int j = b & 31;
    const int i = (b >> 5) & 31;
    const int n = b >> 10;
    const int t = threadIdx.x;
    const int k = t >> 3, lq = t & 7;

    float4 xv[8];
    const float* xb = x + ((size_t)n << 23) + ((size_t)i << 15) + j * 1024 + k * 32 + lq * 4;
    #pragma unroll
    for (int d = 0; d < 8; ++d) xv[d] = *(const float4*)(xb + ((size_t)d << 20));

    const float* U = ws + U3OFF;
    const size_t c012 = (size_t)i * 1024 + j * 32 + k;
    const size_t c013 = (size_t)i * 1024 + j * 32 + lq * 4;
    const size_t c023 = (size_t)i * 1024 + k * 32 + lq * 4;
    const size_t c123 = (size_t)j * 1024 + k * 32 + lq * 4;

    #pragma unroll
    for (int so = 0; so < 8; ++so) {
        const size_t nso = (size_t)(n * 8 + so) << 15;
        const float  u0 = U[0 * R3SZ + nso + c012];
        const float4 u1 = *(const float4*)(U + 1 * R3SZ + nso + c013);
        const float4 u2 = *(const float4*)(U + 2 * R3SZ + nso + c023);
        const float4 u3 = *(const float4*)(U + 3 * R3SZ + nso + c123);
        float4 acc;
        acc.x = u0 + u1.x + u2.x + u3.x;
        acc.y = u0 + u1.y + u2.y + u3.y;
        acc.z = u0 + u1.z + u2.z + u3.z;
        acc.w = u0 + u1.w + u2.w + u3.w;
        #pragma unroll
        for (int d = 0; d < 8; ++d) {
            const float w = c68[d * 8 + so];
            acc.x += w * xv[d].x; acc.y += w * xv[d].y;
            acc.z += w * xv[d].z; acc.w += w * xv[d].w;
        }
        *(float4*)(out + ((size_t)(n * 8 + so) << 20) + ((size_t)i << 15)
                   + j * 1024 + k * 32 + lq * 4) = acc;
    }
}

extern "C" void kernel_launch(void* const* d_in, const int* in_sizes, int n_in,
                              void* d_out, int out_size, void* d_ws, size_t ws_size,
                              hipStream_t stream) {
    const float* x     = (const float*)d_in[0];
    const float* coefs = (const float*)d_in[1];
    const float* bias  = (const float*)d_in[2];
    float* out = (float*)d_out;
    float* ws  = (float*)d_ws;

    // zero the atomically-accumulated regions: red2_23 (16384 f) + red1 (2048 f)
    hipMemsetAsync((void*)(ws + R2OFF + 5 * R2SZ), 0,
                   (R2SZ + 4 * R1SZ) * sizeof(float), stream);
    hipLaunchKernelGGL(k_red3,  dim3(1024), dim3(512), 0, stream, x, ws);
    hipLaunchKernelGGL(k_mixF,  dim3(2048), dim3(256), 0, stream, coefs, bias, ws);
    hipLaunchKernelGGL(k_final, dim3(2048), dim3(256), 0, stream, x, coefs, ws, out);
}